// Round 19
// baseline (102.469 us; speedup 1.0000x reference)
//
#include <hip/hip_runtime.h>
#include <hip/hip_bf16.h>

// Problem constants
#define B_ROWS 4096
#define NN     8192
#define DD     128
#define NTRI   2080         // 64*65/2 upper-triangular tiles
#define CSHIFT 128.0f       // fixed logsumexp shift (log2 domain)

typedef __attribute__((ext_vector_type(8))) short s8v;   // 8 bf16 (4 VGPR)
typedef __attribute__((ext_vector_type(4))) float f4v;   // 4 f32
typedef __attribute__((ext_vector_type(2))) float f2v;
typedef unsigned int u32;
typedef unsigned short u16;
typedef unsigned char u8;

static constexpr float SCALE_H = 1.6986436f;      // sqrt(2*log2(e)); folds /TEMP and log2e into the matmul
static constexpr float SCALE2  = 2.8853900818f;   // 2*log2(e)
static constexpr float LN2     = 0.6931471805599453f;
static constexpr float INV255  = 1.0f / 255.0f;

__device__ __forceinline__ float fast_exp2(float x) {
#if __has_builtin(__builtin_amdgcn_exp2f)
    return __builtin_amdgcn_exp2f(x);      // bare v_exp_f32
#else
    return exp2f(x);
#endif
}

// (1 - x^2) with mask folded in, quantized to u8 (max err 1/510 on s2)
__device__ __forceinline__ u8 s2m_pack8(float x, bool msk) {
    float s2 = msk ? 0.f : 1.f - x * x;    // s2=0 => exp2(-CSHIFT) -> ~0
    return (u8)(s2 * 255.f + 0.5f);
}

__device__ __forceinline__ u16 f2bf(float x) {
    union { __hip_bfloat16 h; u16 u; } cv;
    cv.h = __float2bfloat16(x);
    return cv.u;
}

__device__ __forceinline__ float bf2f(u16 u) {
    return __uint_as_float(((u32)u) << 16);
}

typedef __attribute__((address_space(1))) const u32 gu32;
typedef __attribute__((address_space(3))) u32 lu32;
__device__ __forceinline__ void gload_lds16(const void* g, void* l) {
    // async global->LDS, 16B/lane; dest = lds base + lane*16 (wave-uniform base)
    __builtin_amdgcn_global_load_lds((gu32*)g, (lu32*)l, 16, 0, 0);
}

// ---- kernel 1: fused bf16-prep + pos dot ----
__global__ void hpos_kernel(const float* __restrict__ hi, const float* __restrict__ hj,
                            __hip_bfloat16* __restrict__ hb, float* __restrict__ pos2) {
    int w = threadIdx.x >> 6, l = threadIdx.x & 63;
    int row = blockIdx.x * 4 + w;
    f2v a = ((const f2v*)(hi + (size_t)row * DD))[l];
    f2v b = ((const f2v*)(hj + (size_t)row * DD))[l];
    float d = a[0] * b[0] + a[1] * b[1];
    #pragma unroll
    for (int off = 32; off; off >>= 1) d += __shfl_xor(d, off, 64);
    if (l == 0) pos2[row] = SCALE2 * d;
    union { ushort2 u2; __hip_bfloat16 h[2]; } ua, ub;
    ua.h[0] = __float2bfloat16(a[0] * SCALE_H);
    ua.h[1] = __float2bfloat16(a[1] * SCALE_H);
    ub.h[0] = __float2bfloat16(b[0] * SCALE_H);
    ub.h[1] = __float2bfloat16(b[1] * SCALE_H);
    ((ushort2*)(hb + (size_t)row * DD))[l] = ua.u2;
    ((ushort2*)(hb + (size_t)(row + B_ROWS) * DD))[l] = ub.u2;
}

// ---- kernel 2: symmetric-tile fused sim*S2 + fixed-shift sum-of-exp2 ----
// R16 structure with: (a) u8 s2m panels (sA linear; sB written pre-transposed
// so both reads are [rr*64+cc] contiguous); (b) per-wave partial sums stored
// directly to GLOBAL as bf16 (row-view split 2j+wn; col-view split 4i+wm) --
// no LDS merge, no final barrier. LDS = 32768+4096+4096 = 40960 B exactly
// -> 4 blocks/CU (160 KB), thread-capped at 100% occupancy ceiling.
__global__ __launch_bounds__(512, 4)
void main_kernel(const __hip_bfloat16* __restrict__ hb, const float* __restrict__ S,
                 u16* __restrict__ ssr, u16* __restrict__ ssc) {
    __shared__ short ldsB[128][128];                  // 32 KB B tile (row-swizzled)
    __shared__ __align__(16) u8 sAu[64 * 64];         // 4 KB row-view s2m (u8)
    __shared__ __align__(16) u8 sBtu[64 * 64];        // 4 KB col-view s2m, TRANSPOSED

    // XCD-bijective swizzle (2080 % 8 == 0) + triangular decode (i <= j)
    const int orig = blockIdx.x;
    const int bid  = (orig & 7) * (NTRI / 8) + (orig >> 3);
    int j = (int)((sqrtf(8.0f * (float)bid + 1.0f) - 1.0f) * 0.5f);
    while (((j + 1) * (j + 2)) / 2 <= bid) ++j;   // fixup fp error (exact)
    while ((j * (j + 1)) / 2 > bid) --j;
    const int i = bid - (j * (j + 1)) / 2;
    const bool diag = (i == j);

    const int tid = threadIdx.x;
    const int l  = tid & 63;
    const int w  = tid >> 6;                   // 0..7
    const int wm = w >> 1, wn = w & 1;
    const int lc = l & 15;                     // frag row/col within 16
    const int lk = l >> 4;                     // k-group
    const int r64 = i * 64, c64 = j * 64;

    const s8v* hb8 = (const s8v*)hb;           // 16 x s8v per row of 128 bf16

    // ---- stage B tile (async): 128 hb-rows; 4 gloads/wave
    #pragma unroll
    for (int i2 = 0; i2 < 4; i2++) {
        const int rowb = w * 16 + i2 * 4;
        const int lrw  = rowb + lk;            // local row 0..127
        const int grow = c64 + ((lrw < 64) ? lrw : (lrw - 64 + B_ROWS));
        const int sc16 = lc ^ (lrw & 7);       // source pre-swizzle
        gload_lds16((const char*)hb + ((size_t)grow << 8) + (sc16 << 4),
                    (char*)&ldsB[rowb][0]);
    }

    // ---- pack u8 s2m panels (overlaps B-stage flight, like R16)
    {
        const int prr = tid >> 3;              // 0..63
        const int pc8 = (tid & 7) * 8;         // 0..56
        const float* gA = S + (size_t)(r64 + prr) * B_ROWS + c64 + pc8;
        const float* gB = S + (size_t)(c64 + prr) * B_ROWS + r64 + pc8;
        f4v a0 = ((const f4v*)gA)[0], a1 = ((const f4v*)gA)[1];
        f4v b0 = ((const f4v*)gB)[0], b1 = ((const f4v*)gB)[1];
        union { u8 c[8]; uint2 v; } qa;
        u8 qb[8];
        #pragma unroll
        for (int e = 0; e < 4; e++) {
            qa.c[e]     = s2m_pack8(a0[e], diag && (pc8 + e     == prr));
            qa.c[e + 4] = s2m_pack8(a1[e], diag && (pc8 + 4 + e == prr));
            qb[e]     = s2m_pack8(b0[e], false);   // col-view never read on diag
            qb[e + 4] = s2m_pack8(b1[e], false);
        }
        *(uint2*)&sAu[prr * 64 + pc8] = qa.v;      // 8B contiguous store
        #pragma unroll
        for (int e = 0; e < 8; e++)                // transposed byte scatter
            sBtu[(pc8 + e) * 64 + prr] = qb[e];
    }

    // ---- A fragments: wave's 16 pair-rows x 2 halves
    s8v afr[2][4];
    #pragma unroll
    for (int fm = 0; fm < 2; fm++) {
        int ar = (r64 + wm * 16 + lc) + fm * B_ROWS;
        #pragma unroll
        for (int kk = 0; kk < 4; kk++)
            afr[fm][kk] = hb8[ar * 16 + kk * 4 + lk];
    }
    __syncthreads();   // B tile + panels + afr ready (single barrier)

    // ---- MFMA: 32 per wave (fm2 x fh2 x cg2 x kk4), acc[fm][fh][cg]
    const char* bp[4];
    {
        const char* bb = (const char*)ldsB + (wn * 32 + lc) * 256;
        #pragma unroll
        for (int kk = 0; kk < 4; kk++)
            bp[kk] = bb + (((kk * 4 + lk) ^ (lc & 7)) << 4);
    }
    f4v acc[2][2][2];
    #pragma unroll
    for (int fm = 0; fm < 2; fm++)
        #pragma unroll
        for (int fh = 0; fh < 2; fh++)
            #pragma unroll
            for (int cg = 0; cg < 2; cg++) acc[fm][fh][cg] = f4v{0.f, 0.f, 0.f, 0.f};
    #pragma unroll
    for (int kk = 0; kk < 4; kk++) {
        #pragma unroll
        for (int fh = 0; fh < 2; fh++)
            #pragma unroll
            for (int cg = 0; cg < 2; cg++) {
                s8v bf = *(const s8v*)(bp[kk] + fh * 16384 + cg * 4096);
                acc[0][fh][cg] = __builtin_amdgcn_mfma_f32_16x16x32_bf16(
                    afr[0][kk], bf, acc[0][fh][cg], 0, 0, 0);
                acc[1][fh][cg] = __builtin_amdgcn_mfma_f32_16x16x32_bf16(
                    afr[1][kk], bf, acc[1][fh][cg], 0, 0, 0);
            }
    }

    // ---- dual epilogue: row-view sAu[rr][cc], col-view sBtu[rr][cc] (transposed)
    float rsum[2][4], csum[2][2];
    #pragma unroll
    for (int fm = 0; fm < 2; fm++)
        #pragma unroll
        for (int r = 0; r < 4; r++) rsum[fm][r] = 0.f;
    csum[0][0] = csum[0][1] = csum[1][0] = csum[1][1] = 0.f;

    #pragma unroll
    for (int r = 0; r < 4; r++) {
        const int rr = wm * 16 + lk * 4 + r;
        #pragma unroll
        for (int cg = 0; cg < 2; cg++) {
            const int cc = wn * 32 + cg * 16 + lc;
            const float s2a = (float)sAu[rr * 64 + cc] * INV255;
            const float s2b = (float)sBtu[rr * 64 + cc] * INV255;
            #pragma unroll
            for (int fm = 0; fm < 2; fm++)
                #pragma unroll
                for (int fh = 0; fh < 2; fh++) {
                    const float a = acc[fm][fh][cg][r];
                    rsum[fm][r]  += fast_exp2(fmaf(a, s2a, -CSHIFT));
                    csum[fh][cg] += fast_exp2(fmaf(a, s2b, -CSHIFT));
                }
        }
    }

    // ---- per-wave reduce + DIRECT global bf16 stores (no LDS merge/barrier)
    #pragma unroll
    for (int fm = 0; fm < 2; fm++) {
        #pragma unroll
        for (int r = 0; r < 4; r++) {
            float ss = rsum[fm][r];
            #pragma unroll
            for (int off = 1; off < 16; off <<= 1) ss += __shfl_xor(ss, off, 64);
            if (lc == 0) {    // 4 lanes (lk 0..3), each a distinct row
                int rho = wm * 16 + lk * 4 + r;
                ssr[(size_t)(j * 2 + wn) * NN + (r64 + rho + fm * B_ROWS)] = f2bf(ss);
            }
        }
    }
    #pragma unroll
    for (int fh = 0; fh < 2; fh++) {
        #pragma unroll
        for (int cg = 0; cg < 2; cg++) {
            float ss = csum[fh][cg];
            ss += __shfl_xor(ss, 16, 64);
            ss += __shfl_xor(ss, 32, 64);
            if (l < 16) {     // 16 lanes, contiguous cols
                int cc = wn * 32 + cg * 16 + lc;
                ssc[(size_t)(i * 4 + wm) * NN + (c64 + cc + fh * B_ROWS)] = f2bf(ss);
            }
        }
    }
    // diag blocks' col-view stores land in split 4i+wm, which reduce never
    // reads for rows of tile i (it reads sp < 4i only) -- harmless.
}

// ---- kernel 3a: per-row split sum + lse, block partial sums (parallel) ----
// Row n (tile i): row-view splits 2j+wn for j>=i -> sp in [2i,128);
// col-view splits 4i'+wm for i'<i -> sp in [0,4i). Each slot written once.
__global__ __launch_bounds__(256)
void reduce_kernel(const u16* __restrict__ ssr, const u16* __restrict__ ssc,
                   const float* __restrict__ pos2, float* __restrict__ partial) {
    __shared__ float red[256];
    const int n = blockIdx.x * 256 + threadIdx.x;   // n < 8192
    const int it = (n & (B_ROWS - 1)) >> 6;         // tile index of this row
    float p = pos2[n & (B_ROWS - 1)];
    float Ssum = fast_exp2(p - CSHIFT);             // pos logit seeds the sum
    for (int sp = 2 * it; sp < 128; sp++)
        Ssum += bf2f(ssr[(size_t)sp * NN + n]);
    for (int sp = 0; sp < 4 * it; sp++)
        Ssum += bf2f(ssc[(size_t)sp * NN + n]);
    red[threadIdx.x] = (CSHIFT + log2f(Ssum)) - p;  // log2 units
    __syncthreads();
    for (int st = 128; st; st >>= 1) {
        if (threadIdx.x < st) red[threadIdx.x] += red[threadIdx.x + st];
        __syncthreads();
    }
    if (threadIdx.x == 0) partial[blockIdx.x] = red[0];
}

// ---- kernel 3b: deterministic final sum over 32 partials ----
__global__ void final_kernel(const float* __restrict__ partial, float* __restrict__ out) {
    if (threadIdx.x == 0) {
        float s = 0.f;
        #pragma unroll
        for (int i = 0; i < 32; i++) s += partial[i];
        out[0] = s * (LN2 / (float)NN);
    }
}

extern "C" void kernel_launch(void* const* d_in, const int* in_sizes, int n_in,
                              void* d_out, int out_size, void* d_ws, size_t ws_size,
                              hipStream_t stream) {
    (void)in_sizes; (void)n_in; (void)out_size; (void)ws_size;
    const float* hi = (const float*)d_in[0];
    const float* hj = (const float*)d_in[1];
    const float* S  = (const float*)d_in[2];

    char* ws = (char*)d_ws;
    __hip_bfloat16* hb = (__hip_bfloat16*)ws;                        // 2 MB
    float* pos2   = (float*)(ws + 2097152);                          // 16 KB
    u16*   ssr    = (u16*)(ws + 2097152 + 16384);                    // 2 MB (128 splits bf16)
    u16*   ssc    = (u16*)(ws + 2097152 + 16384 + 2097152);          // 4 MB (256 splits bf16)
    float* partial= (float*)(ws + 2097152 + 16384 + 2097152 + 4194304); // 128 B

    hpos_kernel<<<1024, 256, 0, stream>>>(hi, hj, hb, pos2);
    main_kernel<<<NTRI, 512, 0, stream>>>(hb, S, ssr, ssc);
    reduce_kernel<<<32, 256, 0, stream>>>(ssr, ssc, pos2, partial);
    final_kernel<<<1, 64, 0, stream>>>(partial, (float*)d_out);
}

// Round 20
// 51.232 us; speedup vs baseline: 2.0001x; 2.0001x over previous
//
#include <hip/hip_runtime.h>
#include <hip/hip_bf16.h>

// Problem constants
#define B_ROWS 4096
#define NN     8192
#define DD     128
#define NTRI   2080         // 64*65/2 upper-triangular tiles
#define CSHIFT 128.0f       // fixed logsumexp shift (log2 domain)

typedef __attribute__((ext_vector_type(8))) short s8v;   // 8 bf16 (4 VGPR)
typedef __attribute__((ext_vector_type(4))) float f4v;   // 4 f32
typedef __attribute__((ext_vector_type(2))) float f2v;
typedef unsigned int u32;
typedef unsigned short u16;
typedef unsigned char u8;

static constexpr float SCALE_H = 1.6986436f;      // sqrt(2*log2(e)); folds /TEMP and log2e into the matmul
static constexpr float SCALE2  = 2.8853900818f;   // 2*log2(e)
static constexpr float LN2     = 0.6931471805599453f;
static constexpr float INV255  = 1.0f / 255.0f;

__device__ __forceinline__ float fast_exp2(float x) {
#if __has_builtin(__builtin_amdgcn_exp2f)
    return __builtin_amdgcn_exp2f(x);      // bare v_exp_f32
#else
    return exp2f(x);
#endif
}

// (1 - x^2) with mask folded in, quantized to u8 (max err 1/510 on s2)
__device__ __forceinline__ u8 s2m_pack8(float x, bool msk) {
    float s2 = msk ? 0.f : 1.f - x * x;    // s2=0 => exp2(-CSHIFT) -> ~0
    return (u8)(s2 * 255.f + 0.5f);
}

__device__ __forceinline__ u16 f2bf(float x) {
    union { __hip_bfloat16 h; u16 u; } cv;
    cv.h = __float2bfloat16(x);
    return cv.u;
}

__device__ __forceinline__ float bf2f(u16 u) {
    return __uint_as_float(((u32)u) << 16);
}

typedef __attribute__((address_space(1))) const u32 gu32;
typedef __attribute__((address_space(3))) u32 lu32;
__device__ __forceinline__ void gload_lds16(const void* g, void* l) {
    // async global->LDS, 16B/lane; dest = lds base + lane*16 (wave-uniform base)
    __builtin_amdgcn_global_load_lds((gu32*)g, (lu32*)l, 16, 0, 0);
}

// ---- kernel 1: fused bf16-prep + pos dot ----
__global__ void hpos_kernel(const float* __restrict__ hi, const float* __restrict__ hj,
                            __hip_bfloat16* __restrict__ hb, float* __restrict__ pos2) {
    int w = threadIdx.x >> 6, l = threadIdx.x & 63;
    int row = blockIdx.x * 4 + w;
    f2v a = ((const f2v*)(hi + (size_t)row * DD))[l];
    f2v b = ((const f2v*)(hj + (size_t)row * DD))[l];
    float d = a[0] * b[0] + a[1] * b[1];
    #pragma unroll
    for (int off = 32; off; off >>= 1) d += __shfl_xor(d, off, 64);
    if (l == 0) pos2[row] = SCALE2 * d;
    union { ushort2 u2; __hip_bfloat16 h[2]; } ua, ub;
    ua.h[0] = __float2bfloat16(a[0] * SCALE_H);
    ua.h[1] = __float2bfloat16(a[1] * SCALE_H);
    ub.h[0] = __float2bfloat16(b[0] * SCALE_H);
    ub.h[1] = __float2bfloat16(b[1] * SCALE_H);
    ((ushort2*)(hb + (size_t)row * DD))[l] = ua.u2;
    ((ushort2*)(hb + (size_t)(row + B_ROWS) * DD))[l] = ub.u2;
}

// ---- kernel 2: symmetric-tile fused sim*S2 + fixed-shift sum-of-exp2 ----
// (byte-identical to R18 main) u8 s2m panels; per-wave partials direct to
// global bf16 (row-view split 2j+wn; col-view split 4i+wm); single barrier.
// LDS = 40960 B exactly -> 4 blocks/CU.
__global__ __launch_bounds__(512, 4)
void main_kernel(const __hip_bfloat16* __restrict__ hb, const float* __restrict__ S,
                 u16* __restrict__ ssr, u16* __restrict__ ssc) {
    __shared__ short ldsB[128][128];                  // 32 KB B tile (row-swizzled)
    __shared__ __align__(16) u8 sAu[64 * 64];         // 4 KB row-view s2m (u8)
    __shared__ __align__(16) u8 sBtu[64 * 64];        // 4 KB col-view s2m, TRANSPOSED

    // XCD-bijective swizzle (2080 % 8 == 0) + triangular decode (i <= j)
    const int orig = blockIdx.x;
    const int bid  = (orig & 7) * (NTRI / 8) + (orig >> 3);
    int j = (int)((sqrtf(8.0f * (float)bid + 1.0f) - 1.0f) * 0.5f);
    while (((j + 1) * (j + 2)) / 2 <= bid) ++j;   // fixup fp error (exact)
    while ((j * (j + 1)) / 2 > bid) --j;
    const int i = bid - (j * (j + 1)) / 2;
    const bool diag = (i == j);

    const int tid = threadIdx.x;
    const int l  = tid & 63;
    const int w  = tid >> 6;                   // 0..7
    const int wm = w >> 1, wn = w & 1;
    const int lc = l & 15;                     // frag row/col within 16
    const int lk = l >> 4;                     // k-group
    const int r64 = i * 64, c64 = j * 64;

    const s8v* hb8 = (const s8v*)hb;           // 16 x s8v per row of 128 bf16

    // ---- stage B tile (async): 128 hb-rows; 4 gloads/wave
    #pragma unroll
    for (int i2 = 0; i2 < 4; i2++) {
        const int rowb = w * 16 + i2 * 4;
        const int lrw  = rowb + lk;            // local row 0..127
        const int grow = c64 + ((lrw < 64) ? lrw : (lrw - 64 + B_ROWS));
        const int sc16 = lc ^ (lrw & 7);       // source pre-swizzle
        gload_lds16((const char*)hb + ((size_t)grow << 8) + (sc16 << 4),
                    (char*)&ldsB[rowb][0]);
    }

    // ---- pack u8 s2m panels (overlaps B-stage flight)
    {
        const int prr = tid >> 3;              // 0..63
        const int pc8 = (tid & 7) * 8;         // 0..56
        const float* gA = S + (size_t)(r64 + prr) * B_ROWS + c64 + pc8;
        const float* gB = S + (size_t)(c64 + prr) * B_ROWS + r64 + pc8;
        f4v a0 = ((const f4v*)gA)[0], a1 = ((const f4v*)gA)[1];
        f4v b0 = ((const f4v*)gB)[0], b1 = ((const f4v*)gB)[1];
        union { u8 c[8]; uint2 v; } qa;
        u8 qb[8];
        #pragma unroll
        for (int e = 0; e < 4; e++) {
            qa.c[e]     = s2m_pack8(a0[e], diag && (pc8 + e     == prr));
            qa.c[e + 4] = s2m_pack8(a1[e], diag && (pc8 + 4 + e == prr));
            qb[e]     = s2m_pack8(b0[e], false);   // col-view never read on diag
            qb[e + 4] = s2m_pack8(b1[e], false);
        }
        *(uint2*)&sAu[prr * 64 + pc8] = qa.v;      // 8B contiguous store
        #pragma unroll
        for (int e = 0; e < 8; e++)                // transposed byte scatter
            sBtu[(pc8 + e) * 64 + prr] = qb[e];
    }

    // ---- A fragments: wave's 16 pair-rows x 2 halves
    s8v afr[2][4];
    #pragma unroll
    for (int fm = 0; fm < 2; fm++) {
        int ar = (r64 + wm * 16 + lc) + fm * B_ROWS;
        #pragma unroll
        for (int kk = 0; kk < 4; kk++)
            afr[fm][kk] = hb8[ar * 16 + kk * 4 + lk];
    }
    __syncthreads();   // B tile + panels + afr ready (single barrier)

    // ---- MFMA: 32 per wave (fm2 x fh2 x cg2 x kk4), acc[fm][fh][cg]
    const char* bp[4];
    {
        const char* bb = (const char*)ldsB + (wn * 32 + lc) * 256;
        #pragma unroll
        for (int kk = 0; kk < 4; kk++)
            bp[kk] = bb + (((kk * 4 + lk) ^ (lc & 7)) << 4);
    }
    f4v acc[2][2][2];
    #pragma unroll
    for (int fm = 0; fm < 2; fm++)
        #pragma unroll
        for (int fh = 0; fh < 2; fh++)
            #pragma unroll
            for (int cg = 0; cg < 2; cg++) acc[fm][fh][cg] = f4v{0.f, 0.f, 0.f, 0.f};
    #pragma unroll
    for (int kk = 0; kk < 4; kk++) {
        #pragma unroll
        for (int fh = 0; fh < 2; fh++)
            #pragma unroll
            for (int cg = 0; cg < 2; cg++) {
                s8v bf = *(const s8v*)(bp[kk] + fh * 16384 + cg * 4096);
                acc[0][fh][cg] = __builtin_amdgcn_mfma_f32_16x16x32_bf16(
                    afr[0][kk], bf, acc[0][fh][cg], 0, 0, 0);
                acc[1][fh][cg] = __builtin_amdgcn_mfma_f32_16x16x32_bf16(
                    afr[1][kk], bf, acc[1][fh][cg], 0, 0, 0);
            }
    }

    // ---- dual epilogue: row-view sAu[rr][cc], col-view sBtu[rr][cc]
    float rsum[2][4], csum[2][2];
    #pragma unroll
    for (int fm = 0; fm < 2; fm++)
        #pragma unroll
        for (int r = 0; r < 4; r++) rsum[fm][r] = 0.f;
    csum[0][0] = csum[0][1] = csum[1][0] = csum[1][1] = 0.f;

    #pragma unroll
    for (int r = 0; r < 4; r++) {
        const int rr = wm * 16 + lk * 4 + r;
        #pragma unroll
        for (int cg = 0; cg < 2; cg++) {
            const int cc = wn * 32 + cg * 16 + lc;
            const float s2a = (float)sAu[rr * 64 + cc] * INV255;
            const float s2b = (float)sBtu[rr * 64 + cc] * INV255;
            #pragma unroll
            for (int fm = 0; fm < 2; fm++)
                #pragma unroll
                for (int fh = 0; fh < 2; fh++) {
                    const float a = acc[fm][fh][cg][r];
                    rsum[fm][r]  += fast_exp2(fmaf(a, s2a, -CSHIFT));
                    csum[fh][cg] += fast_exp2(fmaf(a, s2b, -CSHIFT));
                }
        }
    }

    // ---- per-wave reduce + DIRECT global bf16 stores (no LDS merge/barrier)
    #pragma unroll
    for (int fm = 0; fm < 2; fm++) {
        #pragma unroll
        for (int r = 0; r < 4; r++) {
            float ss = rsum[fm][r];
            #pragma unroll
            for (int off = 1; off < 16; off <<= 1) ss += __shfl_xor(ss, off, 64);
            if (lc == 0) {    // 4 lanes (lk 0..3), each a distinct row
                int rho = wm * 16 + lk * 4 + r;
                ssr[(size_t)(j * 2 + wn) * NN + (r64 + rho + fm * B_ROWS)] = f2bf(ss);
            }
        }
    }
    #pragma unroll
    for (int fh = 0; fh < 2; fh++) {
        #pragma unroll
        for (int cg = 0; cg < 2; cg++) {
            float ss = csum[fh][cg];
            ss += __shfl_xor(ss, 16, 64);
            ss += __shfl_xor(ss, 32, 64);
            if (l < 16) {     // 16 lanes, contiguous cols
                int cc = wn * 32 + cg * 16 + lc;
                ssc[(size_t)(i * 4 + wm) * NN + (c64 + cc + fh * B_ROWS)] = f2bf(ss);
            }
        }
    }
}

// ---- kernel 3a: parallel split-sum + lse ----
// 256 blocks x 256 thr; block b owns rows [32b, 32b+32); thread = (r=tid&31,
// s=tid>>5). Thread sums splits sp==s mod 8 in row n's ranges (row-view
// [2it,128), col-view [0,4it)); 32 consecutive n per slice -> 64B coalesced.
// LDS reduce 8 slices -> per-row lse -> block partial (fixed order).
__global__ __launch_bounds__(256)
void reduce_kernel(const u16* __restrict__ ssr, const u16* __restrict__ ssc,
                   const float* __restrict__ pos2, float* __restrict__ partial) {
    __shared__ float red[256];
    const int r = threadIdx.x & 31;
    const int s = threadIdx.x >> 5;
    const int n = blockIdx.x * 32 + r;              // n < 8192
    const int it = (n & (B_ROWS - 1)) >> 6;         // tile index of this row
    float ssum = 0.f;
    for (int sp = 2 * it + s; sp < 128; sp += 8)
        ssum += bf2f(ssr[(size_t)sp * NN + n]);
    for (int sp = s; sp < 4 * it; sp += 8)
        ssum += bf2f(ssc[(size_t)sp * NN + n]);
    red[threadIdx.x] = ssum;
    __syncthreads();
    if (threadIdx.x < 32) {
        float t = 0.f;
        #pragma unroll
        for (int k = 0; k < 8; k++) t += red[threadIdx.x + 32 * k];
        float p = pos2[n & (B_ROWS - 1)];
        float Ssum = t + fast_exp2(p - CSHIFT);     // pos logit seeds the sum
        red[threadIdx.x] = (CSHIFT + log2f(Ssum)) - p;  // log2 units
    }
    __syncthreads();
    if (threadIdx.x == 0) {
        float acc = 0.f;
        #pragma unroll
        for (int k = 0; k < 32; k++) acc += red[k];
        partial[blockIdx.x] = acc;
    }
}

// ---- kernel 3b: deterministic final sum over 256 partials (LDS tree) ----
__global__ __launch_bounds__(256)
void final_kernel(const float* __restrict__ partial, float* __restrict__ out) {
    __shared__ float red[256];
    red[threadIdx.x] = partial[threadIdx.x];
    __syncthreads();
    for (int st = 128; st; st >>= 1) {
        if (threadIdx.x < st) red[threadIdx.x] += red[threadIdx.x + st];
        __syncthreads();
    }
    if (threadIdx.x == 0) out[0] = red[0] * (LN2 / (float)NN);
}

extern "C" void kernel_launch(void* const* d_in, const int* in_sizes, int n_in,
                              void* d_out, int out_size, void* d_ws, size_t ws_size,
                              hipStream_t stream) {
    (void)in_sizes; (void)n_in; (void)out_size; (void)ws_size;
    const float* hi = (const float*)d_in[0];
    const float* hj = (const float*)d_in[1];
    const float* S  = (const float*)d_in[2];

    char* ws = (char*)d_ws;
    __hip_bfloat16* hb = (__hip_bfloat16*)ws;                        // 2 MB
    float* pos2   = (float*)(ws + 2097152);                          // 16 KB
    u16*   ssr    = (u16*)(ws + 2097152 + 16384);                    // 2 MB (128 splits bf16)
    u16*   ssc    = (u16*)(ws + 2097152 + 16384 + 2097152);          // 4 MB (256 splits bf16)
    float* partial= (float*)(ws + 2097152 + 16384 + 2097152 + 4194304); // 1 KB

    hpos_kernel<<<1024, 256, 0, stream>>>(hi, hj, hb, pos2);
    main_kernel<<<NTRI, 512, 0, stream>>>(hb, S, ssr, ssc);
    reduce_kernel<<<256, 256, 0, stream>>>(ssr, ssc, pos2, partial);
    final_kernel<<<1, 256, 0, stream>>>(partial, (float*)d_out);
}